// Round 4
// baseline (504.212 us; speedup 1.0000x reference)
//
#include <hip/hip_runtime.h>
#include <hip/hip_bf16.h>

// Problem constants (fixed by setup_inputs)
#define BATCH 16
#define NHEAD 16
#define DHEAD 128
#define BLK   16
#define MAXB  128
#define MAXS  (MAXB * BLK)   // 2048
#define NSPLIT 8
#define CHUNK  (MAXS / NSPLIT)  // 256 == blockDim
#define SCALE  0.0883883476483184f  // 1/sqrt(128)

// ws layout (floats): [0, 32768) rotated Q; then partials (b,h,split)*(D+2);
// then qmeta (2 ints: counter, n_items); then items.
#define WSQ_FLOATS (BATCH * NHEAD * DHEAD)
#define PART_STRIDE (DHEAD + 2)
#define WSPART_FLOATS (BATCH * NHEAD * NSPLIT * PART_STRIDE)

// ---------------- Kernel 1: RoPE Q/K + scatter K,V into caches ---------------
__global__ void rope_scatter(const float* __restrict__ Q,
                             const float* __restrict__ K,
                             const float* __restrict__ V,
                             float* __restrict__ Kcache,
                             float* __restrict__ Vcache,
                             const float* __restrict__ cosb,
                             const float* __restrict__ sinb,
                             const int* __restrict__ save_slots,
                             float* __restrict__ ws_q) {
    const int bh = blockIdx.x;          // b*NHEAD + h
    const int b  = bh / NHEAD;
    const int h  = bh % NHEAD;
    const int d  = threadIdx.x;         // 0..127

    const float c = cosb[b * DHEAD + d];
    const float s = sinb[b * DHEAD + d];

    const size_t qidx = (size_t)bh * DHEAD + d;
    const float qv = Q[qidx];
    const float qrot = (d < DHEAD / 2) ? -Q[qidx + DHEAD / 2] : Q[qidx - DHEAD / 2];
    ws_q[qidx] = qv * c + qrot * s;

    const float kv = K[qidx];
    const float krot = (d < DHEAD / 2) ? -K[qidx + DHEAD / 2] : K[qidx - DHEAD / 2];
    const float kr = kv * c + krot * s;

    const int slot = save_slots[b];
    const size_t cidx = (size_t)slot * (NHEAD * DHEAD) + (size_t)h * DHEAD + d;
    Kcache[cidx] = kr;
    Vcache[cidx] = V[qidx];
}

// ---------------- Kernel 1b: build dynamic work queue ------------------------
// items: only VALID (b, split, h) chunks, ordered (b, split) outer, h inner
// so the 16 heads touching the same 8KB slot rows are grabbed ~concurrently.
__global__ void init_queue(const int* __restrict__ input_length,
                           int* __restrict__ qmeta,   // [0]=counter [1]=n_items
                           int* __restrict__ items) {
    const int t   = threadIdx.x;      // 256 threads: (b, h)
    const int myb = t >> 4;
    const int myh = t & 15;
    int mypre = 0, myc = 0, tot = 0;
    for (int b = 0; b < BATCH; ++b) {
        const int c = (input_length[b] + CHUNK - 1) / CHUNK;
        if (b < myb)  mypre += c;
        if (b == myb) myc = c;
        tot += c;
    }
    for (int s = 0; s < myc; ++s)
        items[(mypre + s) * NHEAD + myh] = (myb << 16) | (s << 8) | myh;
    if (t == 0) { qmeta[0] = 0; qmeta[1] = tot * NHEAD; }
}

// ---------------- Kernel 2: persistent chain-free flash-decode ---------------
// 2048 co-resident blocks grab valid chunks from the queue until empty.
__global__ __launch_bounds__(256) void attn_partial(
        const float* __restrict__ Kcache,
        const float* __restrict__ Vcache,
        const float* __restrict__ mask,
        const int* __restrict__ input_length,
        const int* __restrict__ block_tables,
        const float* __restrict__ ws_q,
        int* __restrict__ qmeta,
        const int* __restrict__ items,
        float* __restrict__ ws_part) {
    const int tid = threadIdx.x;
    const int hw  = tid >> 5;   // 0..7: softmax unit
    const int ln  = tid & 31;   // lane within unit

    __shared__ int   s_item;
    __shared__ int   sbase[CHUNK];        // per-position float index into caches
    __shared__ float sp[CHUNK];           // raw scores, then probabilities
    __shared__ float sred[8];             // [0..3] wave maxes, [4..7] wave sums
    __shared__ float sacc[8][DHEAD];      // per-unit accumulators

    const int n_items = qmeta[1];

    for (;;) {
        if (tid == 0) s_item = atomicAdd(&qmeta[0], 1);
        __syncthreads();
        const int it = s_item;
        if (it >= n_items) return;
        const int item  = items[it];
        const int b     = item >> 16;
        const int split = (item >> 8) & 255;
        const int h     = item & 255;

        const int L  = input_length[b];
        const int s0 = split * CHUNK;
        const int n  = min(CHUNK, L - s0);

        // ---- phase 0: base offsets (one thread per position) ----
        if (tid < n) {
            const int s = s0 + tid;
            sbase[tid] = block_tables[b * MAXB + (s >> 4)] * (BLK * NHEAD * DHEAD)
                       + (s & (BLK - 1)) * (NHEAD * DHEAD) + h * DHEAD;
        }
        const float4 q = ((const float4*)(ws_q + (size_t)(b * NHEAD + h) * DHEAD))[ln];
        __syncthreads();

        // ---- phase 1: K-pass, raw dot products (fully pipelineable) ----
        #pragma unroll 4
        for (int i = hw; i < n; i += 8) {
            const float4 k = ((const float4*)(Kcache + sbase[i]))[ln];
            float d = k.x * q.x + k.y * q.y + k.z * q.z + k.w * q.w;
            #pragma unroll
            for (int off = 16; off >= 1; off >>= 1)
                d += __shfl_xor(d, off, 64);
            if (ln == 0) sp[i] = d;
        }
        __syncthreads();

        // ---- phase 2: block softmax over sp[0..n) ----
        const float sc = (tid < n) ? sp[tid] * SCALE + mask[(size_t)b * MAXS + s0 + tid]
                                   : -1e30f;
        float wm = sc;
        #pragma unroll
        for (int off = 32; off >= 1; off >>= 1)
            wm = fmaxf(wm, __shfl_xor(wm, off, 64));
        if ((tid & 63) == 0) sred[tid >> 6] = wm;
        __syncthreads();
        const float M = fmaxf(fmaxf(sred[0], sred[1]), fmaxf(sred[2], sred[3]));
        const float p = (tid < n) ? __expf(sc - M) : 0.0f;
        sp[tid] = p;
        float wsum = p;
        #pragma unroll
        for (int off = 32; off >= 1; off >>= 1)
            wsum += __shfl_xor(wsum, off, 64);
        if ((tid & 63) == 0) sred[4 + (tid >> 6)] = wsum;
        __syncthreads();
        const float l = (sred[4] + sred[5]) + (sred[6] + sred[7]);

        // ---- phase 3: V-pass, streaming weighted accumulation ----
        float4 acc = make_float4(0.0f, 0.0f, 0.0f, 0.0f);
        #pragma unroll 4
        for (int i = hw; i < n; i += 8) {
            const float4 v = ((const float4*)(Vcache + sbase[i]))[ln];
            const float pi = sp[i];
            acc.x += pi * v.x;
            acc.y += pi * v.y;
            acc.z += pi * v.z;
            acc.w += pi * v.w;
        }

        // ---- merge 8 units (same M -> plain sum) ----
        ((float4*)sacc[hw])[ln] = acc;
        __syncthreads();
        float* part = ws_part + ((size_t)((b * NHEAD + h) * NSPLIT + split)) * PART_STRIDE;
        if (tid < DHEAD) {
            float a = 0.0f;
            #pragma unroll
            for (int w = 0; w < 8; ++w) a += sacc[w][tid];
            part[tid] = a;
            if (tid == 0) { part[DHEAD] = M; part[DHEAD + 1] = l; }
        }
        __syncthreads();   // protect shared arrays before next grab
    }
}

// ---------------- Kernel 3: combine valid partials -> out --------------------
__global__ void attn_combine(const float* __restrict__ ws_part,
                             const int* __restrict__ input_length,
                             float* __restrict__ out) {
    const int bh = blockIdx.x;
    const int b  = bh >> 4;
    const int d  = threadIdx.x;  // 0..127

    const int ns = (input_length[b] + CHUNK - 1) / CHUNK;  // valid splits
    const float* base = ws_part + (size_t)bh * NSPLIT * PART_STRIDE;

    float M = -1e30f;
    for (int s = 0; s < ns; ++s)
        M = fmaxf(M, base[s * PART_STRIDE + DHEAD]);

    float lsum = 0.0f, a = 0.0f;
    for (int s = 0; s < ns; ++s) {
        const float f = __expf(base[s * PART_STRIDE + DHEAD] - M);
        lsum += base[s * PART_STRIDE + DHEAD + 1] * f;
        a    += base[s * PART_STRIDE + d] * f;
    }
    out[(size_t)bh * DHEAD + d] = a / lsum;
}

extern "C" void kernel_launch(void* const* d_in, const int* in_sizes, int n_in,
                              void* d_out, int out_size, void* d_ws, size_t ws_size,
                              hipStream_t stream) {
    const float* Q       = (const float*)d_in[0];
    const float* K       = (const float*)d_in[1];
    const float* V       = (const float*)d_in[2];
    float*       Kcache  = (float*)d_in[3];   // harness restores inputs each launch
    float*       Vcache  = (float*)d_in[4];
    const float* cosb    = (const float*)d_in[5];
    const float* sinb    = (const float*)d_in[6];
    const float* mask    = (const float*)d_in[7];
    const int*   in_len  = (const int*)d_in[8];
    const int*   slots   = (const int*)d_in[9];
    const int*   btab    = (const int*)d_in[10];
    // d_in[11] = max_s scalar, compile-time constant here

    float* ws_q    = (float*)d_ws;
    float* ws_part = ws_q + WSQ_FLOATS;
    int*   qmeta   = (int*)(ws_part + WSPART_FLOATS);
    int*   qitems  = qmeta + 2;
    float* out     = (float*)d_out;

    rope_scatter<<<BATCH * NHEAD, DHEAD, 0, stream>>>(
        Q, K, V, Kcache, Vcache, cosb, sinb, slots, ws_q);

    init_queue<<<1, 256, 0, stream>>>(in_len, qmeta, qitems);

    attn_partial<<<2048, 256, 0, stream>>>(
        Kcache, Vcache, mask, in_len, btab, ws_q, qmeta, qitems, ws_part);

    attn_combine<<<BATCH * NHEAD, DHEAD, 0, stream>>>(ws_part, in_len, out);
}